// Round 10
// baseline (159.980 us; speedup 1.0000x reference)
//
#include <hip/hip_runtime.h>

typedef __attribute__((ext_vector_type(8))) _Float16 half8;
typedef __attribute__((ext_vector_type(4))) _Float16 half4;
typedef __attribute__((ext_vector_type(4))) float floatx4;

// async global->LDS DMA, 16B per lane; lds must be wave-uniform base (+lane*16 implicit)
__device__ inline void gld16(const _Float16* g, _Float16* lds) {
  __builtin_amdgcn_global_load_lds(
      (const __attribute__((address_space(1))) unsigned int*)g,
      (__attribute__((address_space(3))) unsigned int*)lds, 16, 0, 0);
}

// ---------------- kDescC: descriptor builder, branch-free fill ----------------
// blocks [0,3584): (g 16) x (h 56) x (b 4), 256 threads.
// blocks [3584,4448): fp32->fp16 weight casts.
// tap(k1,k2) at (h',w') = x[row=(k2*56+h')/3+k1-1, col=w'+(k2*56+h')%3-1], zero-pad.
__global__ __launch_bounds__(256) void kDescC(const float* __restrict__ x,
                                              const float* __restrict__ w1,
                                              const float* __restrict__ w2,
                                              const float* __restrict__ w3,
                                              _Float16* __restrict__ descF,
                                              _Float16* __restrict__ w1f,
                                              _Float16* __restrict__ w2f,
                                              _Float16* __restrict__ w3f) {
  const int bid = blockIdx.x;
  const int t = threadIdx.x;

  if (bid >= 3584) {                    // ---- weight-cast blocks ----
    int i = (bid - 3584) * 256 + t;
    if (i < 202752) w1f[i] = (_Float16)w1[i];
    else if (i < 211968) w2f[i - 202752] = (_Float16)w2[i - 202752];
    else if (i < 221184) w3f[i - 211968] = (_Float16)w3[i - 211968];
    return;
  }

  int g = bid & 15;
  int h = (bid >> 4) % 56;
  int b = bid / 896;

  // xb row stride = 72 halves (144 B). chunk c (8 halves) stored at c ^ (kk&7).
  __shared__ __align__(16) _Float16 xb[144 * 72];   // 20736 B
  __shared__ __align__(16) int tOf[132][4];         // enc = row*144 | key (key=(row>>4)&7)

  // ---- tap-offset table (132 threads) ----
  if (t < 132) {
    int dl = t;
    int r0, r1, r2, r3;
    if (dl < 36) {                       // x1: max over 4 sub-channels
      int a3 = dl / 9, rem = dl % 9, k1 = rem / 3, k2 = rem % 3;
      int br = (k2 * 3 + k1) * 16 + a3;
      r0 = br; r1 = br + 4; r2 = br + 8; r3 = br + 12;
    } else if (dl < 84) {                // x2: max over k1
      int u = dl - 36, gc = u / 3, k2 = u % 3;
      r0 = (k2 * 3 + 0) * 16 + gc;
      r1 = (k2 * 3 + 1) * 16 + gc;
      r2 = (k2 * 3 + 2) * 16 + gc;
      r3 = r0;
    } else {                             // x3: max over k2
      int u = dl - 84, gc = u / 3, k1 = u % 3;
      r0 = (0 + k1) * 16 + gc;
      r1 = (3 + k1) * 16 + gc;
      r2 = (6 + k1) * 16 + gc;
      r3 = r0;
    }
    tOf[dl][0] = r0 * 144 + ((r0 >> 4) & 7);
    tOf[dl][1] = r1 * 144 + ((r1 >> 4) & 7);
    tOf[dl][2] = r2 * 144 + ((r2 >> 4) & 7);
    tOf[dl][3] = r3 * 144 + ((r3 >> 4) & 7);
  }

  // ---- fill xb: branch-free. interior 1728 units (c4=1..12) + boundary 288 units ----
  {
    const long xp = ((long)b * 256 + g * 16) * 3136;
    // interior: unconditional dwordx4 from row-clamped address; cols always in [3,52]
#pragma unroll
    for (int i = 0; i < 7; ++i) {
      int idx = t + i * 256;
      if (idx < 1728) {
        int r = (idx * 2731) >> 15;     // idx/12 (exact for idx<1792)
        int c4 = idx - r * 12 + 1;      // 1..12
        int kk = r >> 4, ch = r & 15;
        int k2 = (kk >= 6) ? 2 : (kk >= 3 ? 1 : 0);
        int k1 = kk - 3 * k2;
        int t2 = k2 * 56 + h;
        int q3 = (t2 * 683) >> 11;      // t2/3 (exact for t2<168)
        int s = t2 - q3 * 3;
        int gr = q3 + k1 - 1;
        int grc = min(max(gr, 0), 55);
        const float* rp = x + xp + (long)ch * 3136 + (long)grc * 56 + (s - 1) + c4 * 4;
        float fv[4];
        __builtin_memcpy(fv, rp, 16);
        bool rok = (unsigned)gr < 56u;
        half4 hv;
        hv[0] = (_Float16)(rok ? fv[0] : 0.f);
        hv[1] = (_Float16)(rok ? fv[1] : 0.f);
        hv[2] = (_Float16)(rok ? fv[2] : 0.f);
        hv[3] = (_Float16)(rok ? fv[3] : 0.f);
        int chunk = (c4 >> 1) ^ (kk & 7);
        *(half4*)((char*)xb + r * 144 + chunk * 16 + (c4 & 1) * 8) = hv;
      }
    }
    // boundary: c4 in {0,13}; clamped scalar loads + selects, no branches
#pragma unroll
    for (int i = 0; i < 2; ++i) {
      int idx = t + i * 256;
      if (idx < 288) {
        int r = idx >> 1;
        int c4 = (idx & 1) ? 13 : 0;
        int kk = r >> 4, ch = r & 15;
        int k2 = (kk >= 6) ? 2 : (kk >= 3 ? 1 : 0);
        int k1 = kk - 3 * k2;
        int t2 = k2 * 56 + h;
        int q3 = (t2 * 683) >> 11;
        int s = t2 - q3 * 3;
        int gr = q3 + k1 - 1;
        int grc = min(max(gr, 0), 55);
        bool rok = (unsigned)gr < 56u;
        const float* rp = x + xp + (long)ch * 3136 + (long)grc * 56;
        half4 hv;
#pragma unroll
        for (int e = 0; e < 4; ++e) {
          int cg = c4 * 4 + e + s - 1;
          int cgc = min(max(cg, 0), 55);
          float v = rp[cgc];
          hv[e] = (_Float16)((rok & ((unsigned)cg < 56u)) ? v : 0.f);
        }
        int chunk = (c4 >> 1) ^ (kk & 7);
        *(half4*)((char*)xb + r * 144 + chunk * 16 + (c4 & 1) * 8) = hv;
      }
    }
  }
  __syncthreads();

  // ---- compute + transpose + store: 231 units = (pc 0..6) x (dlc 0..32) ----
  const long m00 = ((long)(b * 56 + h)) * 56;
  if (t < 231) {
    int pc = t / 33, dlc = t - pc * 33;
    int dl0 = dlc * 4;
    half8 r8s[4];
    const char* xbb = (const char*)xb;
#pragma unroll
    for (int i = 0; i < 4; ++i) {
      const int4 of = *(const int4*)tOf[dl0 + i];
      half8 v0 = *(const half8*)(xbb + (of.x & ~15) + ((pc ^ (of.x & 15)) << 4));
      half8 v1 = *(const half8*)(xbb + (of.y & ~15) + ((pc ^ (of.y & 15)) << 4));
      half8 v2 = *(const half8*)(xbb + (of.z & ~15) + ((pc ^ (of.z & 15)) << 4));
      half8 v3 = *(const half8*)(xbb + (of.w & ~15) + ((pc ^ (of.w & 15)) << 4));
      half8 a = __builtin_elementwise_max(v0, v1);
      half8 c = __builtin_elementwise_max(v2, v3);
      r8s[i] = __builtin_elementwise_max(a, c);
    }
    int dg0 = (dlc < 9)  ? (g * 36 + dl0)
            : (dlc < 21) ? (576 + g * 48 + (dl0 - 36))
                         : (1344 + g * 48 + (dl0 - 84));
    _Float16* dp = descF + (m00 + pc * 8) * 2112 + dg0;
#pragma unroll
    for (int e = 0; e < 8; ++e) {
      half4 o;
      o[0] = r8s[0][e]; o[1] = r8s[1][e]; o[2] = r8s[2][e]; o[3] = r8s[3][e];
      *(half4*)(dp + (long)e * 2112) = o;   // 8B store, 8B-aligned
    }
  }
}

// ---------------- kGemm1: split-K partial GEMM, LDS-staged via global_load_lds ----------
// grid = 196 Mtiles x 6 K-chunks = 1176 blocks; 256 threads; M=64, N=96, K-chunk=352, BK=32.
__global__ __launch_bounds__(256) void kGemm1(
    const _Float16* __restrict__ descF, const _Float16* __restrict__ w1f,
    _Float16* __restrict__ pacc) {
  __shared__ _Float16 Ab[2][64 * 32];   // [row*32 + c*8]
  __shared__ _Float16 Bb[2][96 * 32];   // [n*32 + c*8]
  const int t = threadIdx.x;
  const int wv = t >> 6, lane = t & 63, quad = lane >> 4, lr = lane & 15;
  const int mt = blockIdx.x / 6, ck = blockIdx.x % 6;
  const long mblk = (long)mt * 64;

  const long agbase = (mblk + (t >> 2)) * 2112 + ck * 352 + (t & 3) * 8;
  const long bg0 = (long)(t >> 2) * 2112 + ck * 352 + (t & 3) * 8;
  const long bg1 = (long)((256 + t) >> 2) * 2112 + ck * 352 + (t & 3) * 8;
  const int wslot = (t >> 6) * 512;     // wave-uniform LDS base (halves)

  floatx4 acc[6];
#pragma unroll
  for (int j = 0; j < 6; ++j) acc[j] = {0.f, 0.f, 0.f, 0.f};

  gld16(descF + agbase, &Ab[0][wslot]);
  gld16(w1f + bg0, &Bb[0][wslot]);
  if (t < 128) gld16(w1f + bg1, &Bb[0][2048 + wslot]);

  int buf = 0;
  for (int kt = 0; kt < 11; ++kt) {
    __syncthreads();
    if (kt < 10) {
      int off = (kt + 1) * 32;
      gld16(descF + agbase + off, &Ab[buf ^ 1][wslot]);
      gld16(w1f + bg0 + off, &Bb[buf ^ 1][wslot]);
      if (t < 128) gld16(w1f + bg1 + off, &Bb[buf ^ 1][2048 + wslot]);
    }
    half8 af = *(const half8*)(&Ab[buf][(wv * 16 + lr) * 32 + quad * 8]);
#pragma unroll
    for (int j = 0; j < 6; ++j) {
      half8 bf = *(const half8*)(&Bb[buf][(j * 16 + lr) * 32 + quad * 8]);
      acc[j] = __builtin_amdgcn_mfma_f32_16x16x32_f16(af, bf, acc[j], 0, 0, 0);
    }
    buf ^= 1;
  }

  _Float16* pp = pacc + (long)(ck * 196 + mt) * 6144;
#pragma unroll
  for (int j = 0; j < 6; ++j)
#pragma unroll
    for (int r = 0; r < 4; ++r)
      pp[(wv * 16 + quad * 4 + r) * 96 + j * 16 + lr] = (_Float16)acc[j][r];
}

// ---------------- kGemm2 v2: reduce(6 pacc)+BN+ReLU -> y tile -> GEMM2 -> softmax ------
// grid = 392 blocks x 256 threads; 32 rows per block; waves = 2(row-half) x 2(col-half).
__global__ __launch_bounds__(256) void kGemm2(
    const _Float16* __restrict__ pacc,
    const float* __restrict__ gamma, const float* __restrict__ beta,
    const float* __restrict__ mean, const float* __restrict__ var,
    const _Float16* __restrict__ w2f, const _Float16* __restrict__ w3f,
    const float* __restrict__ b2, const float* __restrict__ b3,
    _Float16* __restrict__ wtg) {
  __shared__ __align__(16) char smem[24576];
  _Float16* ytF = (_Float16*)smem;        // [0, 6656): 32*104 fp16 (dead after MFMA loop)
  float* wal = (float*)smem;              // [0, 12288): 32*96 f32 (after ytF dead)
  float* wbl = wal + 3072;                // [12288, 24576)
  __shared__ float invv[96], biasv[96];

  const int t = threadIdx.x;
  const int wv = t >> 6, lane = t & 63, quad = lane >> 4, lr = lane & 15;
  const int wr = wv & 1, wc = wv >> 1;
  const long mblk = (long)blockIdx.x * 32;

  if (t < 96) {
    float iv = gamma[t] * rsqrtf(var[t] + 1e-5f);
    invv[t] = iv; biasv[t] = beta[t] - mean[t] * iv;
  }
  __syncthreads();

  // stage: sum 6 split-K slices + BN + ReLU -> ytF [32][104]; 768 quads / 256 threads
#pragma unroll
  for (int i = 0; i < 3; ++i) {
    int q = t + i * 256;                  // 0..767
    int m = q / 24, nq = (q - m * 24) * 4;
    long gbase = (mblk + m) * 96 + nq;
    float s0 = 0.f, s1 = 0.f, s2 = 0.f, s3 = 0.f;
#pragma unroll
    for (int ck = 0; ck < 6; ++ck) {
      half4 v = *(const half4*)(pacc + (long)ck * 1204224 + gbase);
      s0 += (float)v.x; s1 += (float)v.y; s2 += (float)v.z; s3 += (float)v.w;
    }
    half4 o;
    o.x = (_Float16)fmaxf(s0 * invv[nq + 0] + biasv[nq + 0], 0.f);
    o.y = (_Float16)fmaxf(s1 * invv[nq + 1] + biasv[nq + 1], 0.f);
    o.z = (_Float16)fmaxf(s2 * invv[nq + 2] + biasv[nq + 2], 0.f);
    o.w = (_Float16)fmaxf(s3 * invv[nq + 3] + biasv[nq + 3], 0.f);
    *(half4*)(ytF + m * 104 + nq) = o;
  }
  __syncthreads();

  floatx4 aa[3], ab[3];
#pragma unroll
  for (int j = 0; j < 3; ++j) { aa[j] = {0.f,0.f,0.f,0.f}; ab[j] = {0.f,0.f,0.f,0.f}; }
#pragma unroll
  for (int ks = 0; ks < 3; ++ks) {
    half8 af = *(const half8*)(ytF + (wr * 16 + lr) * 104 + ks * 32 + quad * 8);
#pragma unroll
    for (int j = 0; j < 3; ++j) {
      int n = (wc * 3 + j) * 16 + lr;
      int wo = n * 96 + ks * 32 + quad * 8;
      half8 b2v = *(const half8*)(w2f + wo);
      half8 b3v = *(const half8*)(w3f + wo);
      aa[j] = __builtin_amdgcn_mfma_f32_16x16x32_f16(af, b2v, aa[j], 0, 0, 0);
      ab[j] = __builtin_amdgcn_mfma_f32_16x16x32_f16(af, b3v, ab[j], 0, 0, 0);
    }
  }
  __syncthreads();   // ytF dead; smem becomes wal/wbl

#pragma unroll
  for (int j = 0; j < 3; ++j) {
    int n = (wc * 3 + j) * 16 + lr;
    float bb2 = b2[n], bb3 = b3[n];
#pragma unroll
    for (int r = 0; r < 4; ++r) {
      int m = wr * 16 + quad * 4 + r;
      wal[m * 96 + n] = aa[j][r] + bb2;
      wbl[m * 96 + n] = ab[j][r] + bb3;
    }
  }
  __syncthreads();

  // softmax: 32 rows x 64 (g,ns) units = 2048 / 256 threads
#pragma unroll
  for (int it = 0; it < 8; ++it) {
    int u = t + it * 256;
    int m = u >> 6, rest = u & 63;
    int g = rest >> 2, ns = rest & 3;
    int ns1 = ns >> 1, ns2 = ns & 1;
    float la[3], lb[3];
#pragma unroll
    for (int k = 0; k < 3; ++k) {
      la[k] = wal[m * 96 + (g * 3 + k) * 2 + ns1];
      lb[k] = wbl[m * 96 + (g * 3 + k) * 2 + ns2];
    }
    float lg[9], mx = -1e30f;
#pragma unroll
    for (int k1 = 0; k1 < 3; ++k1)
#pragma unroll
      for (int k2 = 0; k2 < 3; ++k2) {
        float v = la[k1] * lb[k2];
        lg[k1 * 3 + k2] = v;
        mx = v > mx ? v : mx;
      }
    float s = 0.f;
#pragma unroll
    for (int k = 0; k < 9; ++k) { lg[k] = __expf(lg[k] - mx); s += lg[k]; }
    float sc = 1.f / (9.f * s);
    _Float16* dst = wtg + (mblk + m) * 576 + g * 36 + ns * 9;
#pragma unroll
    for (int k = 0; k < 9; ++k) dst[k] = (_Float16)(lg[k] * sc);
  }
}

// ---------------- kApply v3: merged-wh, shift-folded branch-free fill ----------
// block = (b, h, g): 3584 blocks, 256 threads; 16 channels, all 56 w-positions.
// xr[kk 9][cl 16][60] fp16 holds x tap rows with per-k2 column shift folded
// (col p of row kk = global col p + s(k2) - 1, zero-padded).
__global__ __launch_bounds__(256) void kApply(const float* __restrict__ x,
                                              const _Float16* __restrict__ wt,
                                              float* __restrict__ out) {
  int bid = blockIdx.x;
  int g = bid & 15;
  int h = (bid >> 4) % 56;
  int b = bid / 896;
  int cbase = g * 16;

  __shared__ __align__(16) _Float16 xr[9 * 16 * 60];   // 17280 B, row stride 60 halves
  __shared__ __align__(16) float wtb[56 * 36];         // 8064 B, [p*36 + (k1*3+k2)*4 + ns]
  __shared__ float ob[32 * 114];                       // 14592 B, [(cl*2+ns1)*114 + p*2+ns2]

  int t = threadIdx.x;

  // ---- fill xr: 144 rows x 56 cols, shift folded; interior dwordx4 + boundary ----
  {
    const long xp = ((long)b * 256 + cbase) * 3136;
    // interior: c4 = 1..12, cols (s-1)+c4*4+e in [3,52] — always in-bounds
#pragma unroll
    for (int i = 0; i < 7; ++i) {
      int idx = t + i * 256;
      if (idx < 1728) {
        int r = (idx * 2731) >> 15;     // idx/12
        int c4 = idx - r * 12 + 1;      // 1..12
        int kk = r >> 4, cl = r & 15;
        int k2 = (kk >= 6) ? 2 : (kk >= 3 ? 1 : 0);
        int k1 = kk - 3 * k2;
        int t2 = k2 * 56 + h;
        int q3 = (t2 * 683) >> 11;      // t2/3
        int s = t2 - q3 * 3;
        int gr = q3 + k1 - 1;
        int grc = min(max(gr, 0), 55);
        const float* rp = x + xp + (long)cl * 3136 + (long)grc * 56 + (s - 1) + c4 * 4;
        float fv[4];
        __builtin_memcpy(fv, rp, 16);
        bool rok = (unsigned)gr < 56u;
        half4 hv;
        hv[0] = (_Float16)(rok ? fv[0] : 0.f);
        hv[1] = (_Float16)(rok ? fv[1] : 0.f);
        hv[2] = (_Float16)(rok ? fv[2] : 0.f);
        hv[3] = (_Float16)(rok ? fv[3] : 0.f);
        *(half4*)((char*)xr + r * 120 + c4 * 8) = hv;
      }
    }
    // boundary: c4 in {0,13}; clamped scalar loads + selects
#pragma unroll
    for (int i = 0; i < 2; ++i) {
      int idx = t + i * 256;
      if (idx < 288) {
        int r = idx >> 1;
        int c4 = (idx & 1) ? 13 : 0;
        int kk = r >> 4, cl = r & 15;
        int k2 = (kk >= 6) ? 2 : (kk >= 3 ? 1 : 0);
        int k1 = kk - 3 * k2;
        int t2 = k2 * 56 + h;
        int q3 = (t2 * 683) >> 11;
        int s = t2 - q3 * 3;
        int gr = q3 + k1 - 1;
        int grc = min(max(gr, 0), 55);
        bool rok = (unsigned)gr < 56u;
        const float* rp = x + xp + (long)cl * 3136 + (long)grc * 56;
        half4 hv;
#pragma unroll
        for (int e = 0; e < 4; ++e) {
          int cg = c4 * 4 + e + s - 1;
          int cgc = min(max(cg, 0), 55);
          float v = rp[cgc];
          hv[e] = (_Float16)((rok & ((unsigned)cg < 56u)) ? v : 0.f);
        }
        *(half4*)((char*)xr + r * 120 + c4 * 8) = hv;
      }
    }
  }

  // ---- wt -> wtb: 504 units = (p 0..55, j 0..8), half4 loads + register transpose ----
  {
    long m0 = ((long)(b * 56 + h)) * 56;
#pragma unroll
    for (int i = 0; i < 2; ++i) {
      int idx = t + i * 256;
      if (idx < 504) {
        int p = idx / 9, j = idx - p * 9;
        half4 v = *(const half4*)(wt + (m0 + p) * 576 + g * 36 + j * 4);
#pragma unroll
        for (int e = 0; e < 4; ++e) {
          int u = j * 4 + e;            // 0..35
          int ns = (u * 57) >> 9;       // u/9
          int kk = u - ns * 9;
          wtb[p * 36 + kk * 4 + ns] = (float)v[e];
        }
      }
    }
  }
  __syncthreads();

  // ---- compute: unit (cl, p) over 16x56 = 896; 4 ns accumulators; float4 wt reads ----
#pragma unroll
  for (int i = 0; i < 4; ++i) {
    int idx = i * 256 + t;
    if (idx < 896) {
      int cl = idx & 15;
      int p = idx >> 4;                 // 0..55
      float a0 = 0.f, a1 = 0.f, a2 = 0.f, a3 = 0.f;
#pragma unroll
      for (int k1 = 0; k1 < 3; ++k1)
#pragma unroll
        for (int k2 = 0; k2 < 3; ++k2) {
          float xv = (float)xr[((k2 * 3 + k1) * 16 + cl) * 60 + p];
          float4 wv = *(const float4*)&wtb[p * 36 + (k1 * 3 + k2) * 4];
          a0 += xv * wv.x; a1 += xv * wv.y; a2 += xv * wv.z; a3 += xv * wv.w;
        }
      int ob0 = cl * 228 + p * 2;       // (cl*2)*114 + p*2
      ob[ob0] = a0;
      ob[ob0 + 1] = a1;
      ob[ob0 + 114] = a2;
      ob[ob0 + 115] = a3;
    }
  }
  __syncthreads();

  // ---- writeout: 32 rows x 56 float2 cols, coalesced ----
  {
    const long obase = (((long)b * 256 + cbase) * 112 + 2 * h) * 112;
#pragma unroll
    for (int i = 0; i < 7; ++i) {
      int u = t + i * 256;              // 0..1791 = (row 32) x (wo2 56)
      int row = u / 56, wo2 = u - row * 56;
      int cli = row >> 1, n1 = row & 1;
      float2 v = *(const float2*)&ob[row * 114 + wo2 * 2];
      *(float2*)&out[obase + cli * 12544 + n1 * 112 + wo2 * 2] = v;
    }
  }
}

extern "C" void kernel_launch(void* const* d_in, const int* in_sizes, int n_in,
                              void* d_out, int out_size, void* d_ws, size_t ws_size,
                              hipStream_t stream) {
  const float* x = (const float*)d_in[0];
  const float* w1 = (const float*)d_in[1];
  const float* gamma = (const float*)d_in[2];
  const float* beta = (const float*)d_in[3];
  const float* mean = (const float*)d_in[4];
  const float* var = (const float*)d_in[5];
  const float* w2 = (const float*)d_in[6];
  const float* b2 = (const float*)d_in[7];
  const float* w3 = (const float*)d_in[8];
  const float* b3 = (const float*)d_in[9];
  float* out = (float*)d_out;

  // workspace layout (bytes), total ~82 MB:
  //   w1f fp16:   [0, 405504)
  //   w2f fp16:   [405504, 423936)
  //   w3f fp16:   [423936, 442368)
  //   wtg fp16:   [442368, 14893056)
  //   descF fp16: [14893056, 67878912)
  //   pacc fp16:  [67878912, 82329600)   (6 split-K slices)
  _Float16* w1f = (_Float16*)d_ws;
  _Float16* w2f = w1f + 202752;
  _Float16* w3f = w2f + 9216;
  _Float16* wtg = (_Float16*)((char*)d_ws + 442368);
  _Float16* descF = (_Float16*)((char*)d_ws + 14893056);
  _Float16* pacc = (_Float16*)((char*)d_ws + 67878912);

  hipLaunchKernelGGL(kDescC, dim3(4448), dim3(256), 0, stream,
                     x, w1, w2, w3, descF, w1f, w2f, w3f);
  hipLaunchKernelGGL(kGemm1, dim3(1176), dim3(256), 0, stream, descF, w1f, pacc);
  hipLaunchKernelGGL(kGemm2, dim3(392), dim3(256), 0, stream,
                     pacc, gamma, beta, mean, var, w2f, w3f, b2, b3, wtg);
  hipLaunchKernelGGL(kApply, dim3(3584), dim3(256), 0, stream, x, wtg, out);
}

// Round 11
// 149.528 us; speedup vs baseline: 1.0699x; 1.0699x over previous
//
#include <hip/hip_runtime.h>

typedef __attribute__((ext_vector_type(8))) _Float16 half8;
typedef __attribute__((ext_vector_type(4))) _Float16 half4;
typedef __attribute__((ext_vector_type(4))) float floatx4;

// async global->LDS DMA, 16B per lane; lds must be wave-uniform base (+lane*16 implicit)
__device__ inline void gld16(const _Float16* g, _Float16* lds) {
  __builtin_amdgcn_global_load_lds(
      (const __attribute__((address_space(1))) unsigned int*)g,
      (__attribute__((address_space(3))) unsigned int*)lds, 16, 0, 0);
}

// ---------------- kDescC: descriptor builder, branch-free fill ----------------
// blocks [0,3584): (g 16) x (h 56) x (b 4), 256 threads.
// blocks [3584,3800): fp32->fp16 weight casts, float4-vectorized (4 elems/thread).
// tap(k1,k2) at (h',w') = x[row=(k2*56+h')/3+k1-1, col=w'+(k2*56+h')%3-1], zero-pad.
__global__ __launch_bounds__(256) void kDescC(const float* __restrict__ x,
                                              const float* __restrict__ w1,
                                              const float* __restrict__ w2,
                                              const float* __restrict__ w3,
                                              _Float16* __restrict__ descF,
                                              _Float16* __restrict__ w1f,
                                              _Float16* __restrict__ w2f,
                                              _Float16* __restrict__ w3f) {
  const int bid = blockIdx.x;
  const int t = threadIdx.x;

  if (bid >= 3584) {                    // ---- weight-cast blocks (vectorized) ----
    int u = (bid - 3584) * 256 + t;     // quad index, 55296 total
    const float* src;
    _Float16* dst;
    int off;
    if (u < 50688) { src = w1; dst = w1f; off = u * 4; }
    else if (u < 52992) { src = w2; dst = w2f; off = (u - 50688) * 4; }
    else { src = w3; dst = w3f; off = (u - 52992) * 4; }
    float4 v = *(const float4*)(src + off);
    half4 o;
    o[0] = (_Float16)v.x; o[1] = (_Float16)v.y;
    o[2] = (_Float16)v.z; o[3] = (_Float16)v.w;
    *(half4*)(dst + off) = o;
    return;
  }

  int g = bid & 15;
  int h = (bid >> 4) % 56;
  int b = bid / 896;

  // xb row stride = 72 halves (144 B). chunk c (8 halves) stored at c ^ (kk&7).
  __shared__ __align__(16) _Float16 xb[144 * 72];   // 20736 B
  __shared__ __align__(16) int tOf[132][4];         // enc = row*144 | key (key=(row>>4)&7)

  // ---- tap-offset table (132 threads) ----
  if (t < 132) {
    int dl = t;
    int r0, r1, r2, r3;
    if (dl < 36) {                       // x1: max over 4 sub-channels
      int a3 = dl / 9, rem = dl % 9, k1 = rem / 3, k2 = rem % 3;
      int br = (k2 * 3 + k1) * 16 + a3;
      r0 = br; r1 = br + 4; r2 = br + 8; r3 = br + 12;
    } else if (dl < 84) {                // x2: max over k1
      int u = dl - 36, gc = u / 3, k2 = u % 3;
      r0 = (k2 * 3 + 0) * 16 + gc;
      r1 = (k2 * 3 + 1) * 16 + gc;
      r2 = (k2 * 3 + 2) * 16 + gc;
      r3 = r0;
    } else {                             // x3: max over k2
      int u = dl - 84, gc = u / 3, k1 = u % 3;
      r0 = (0 + k1) * 16 + gc;
      r1 = (3 + k1) * 16 + gc;
      r2 = (6 + k1) * 16 + gc;
      r3 = r0;
    }
    tOf[dl][0] = r0 * 144 + ((r0 >> 4) & 7);
    tOf[dl][1] = r1 * 144 + ((r1 >> 4) & 7);
    tOf[dl][2] = r2 * 144 + ((r2 >> 4) & 7);
    tOf[dl][3] = r3 * 144 + ((r3 >> 4) & 7);
  }

  // ---- fill xb: branch-free. interior 1728 units (c4=1..12) + boundary 288 units ----
  {
    const long xp = ((long)b * 256 + g * 16) * 3136;
    // interior: unconditional dwordx4 from row-clamped address; cols always in [3,52]
#pragma unroll
    for (int i = 0; i < 7; ++i) {
      int idx = t + i * 256;
      if (idx < 1728) {
        int r = (idx * 2731) >> 15;     // idx/12 (exact for idx<1792)
        int c4 = idx - r * 12 + 1;      // 1..12
        int kk = r >> 4, ch = r & 15;
        int k2 = (kk >= 6) ? 2 : (kk >= 3 ? 1 : 0);
        int k1 = kk - 3 * k2;
        int t2 = k2 * 56 + h;
        int q3 = (t2 * 683) >> 11;      // t2/3 (exact for t2<168)
        int s = t2 - q3 * 3;
        int gr = q3 + k1 - 1;
        int grc = min(max(gr, 0), 55);
        const float* rp = x + xp + (long)ch * 3136 + (long)grc * 56 + (s - 1) + c4 * 4;
        float fv[4];
        __builtin_memcpy(fv, rp, 16);
        bool rok = (unsigned)gr < 56u;
        half4 hv;
        hv[0] = (_Float16)(rok ? fv[0] : 0.f);
        hv[1] = (_Float16)(rok ? fv[1] : 0.f);
        hv[2] = (_Float16)(rok ? fv[2] : 0.f);
        hv[3] = (_Float16)(rok ? fv[3] : 0.f);
        int chunk = (c4 >> 1) ^ (kk & 7);
        *(half4*)((char*)xb + r * 144 + chunk * 16 + (c4 & 1) * 8) = hv;
      }
    }
    // boundary: c4 in {0,13}; clamped scalar loads + selects, no branches
#pragma unroll
    for (int i = 0; i < 2; ++i) {
      int idx = t + i * 256;
      if (idx < 288) {
        int r = idx >> 1;
        int c4 = (idx & 1) ? 13 : 0;
        int kk = r >> 4, ch = r & 15;
        int k2 = (kk >= 6) ? 2 : (kk >= 3 ? 1 : 0);
        int k1 = kk - 3 * k2;
        int t2 = k2 * 56 + h;
        int q3 = (t2 * 683) >> 11;
        int s = t2 - q3 * 3;
        int gr = q3 + k1 - 1;
        int grc = min(max(gr, 0), 55);
        bool rok = (unsigned)gr < 56u;
        const float* rp = x + xp + (long)ch * 3136 + (long)grc * 56;
        half4 hv;
#pragma unroll
        for (int e = 0; e < 4; ++e) {
          int cg = c4 * 4 + e + s - 1;
          int cgc = min(max(cg, 0), 55);
          float v = rp[cgc];
          hv[e] = (_Float16)((rok & ((unsigned)cg < 56u)) ? v : 0.f);
        }
        int chunk = (c4 >> 1) ^ (kk & 7);
        *(half4*)((char*)xb + r * 144 + chunk * 16 + (c4 & 1) * 8) = hv;
      }
    }
  }
  __syncthreads();

  // ---- compute + transpose + store: 231 units = (pc 0..6) x (dlc 0..32) ----
  const long m00 = ((long)(b * 56 + h)) * 56;
  if (t < 231) {
    int pc = t / 33, dlc = t - pc * 33;
    int dl0 = dlc * 4;
    half8 r8s[4];
    const char* xbb = (const char*)xb;
#pragma unroll
    for (int i = 0; i < 4; ++i) {
      const int4 of = *(const int4*)tOf[dl0 + i];
      half8 v0 = *(const half8*)(xbb + (of.x & ~15) + ((pc ^ (of.x & 15)) << 4));
      half8 v1 = *(const half8*)(xbb + (of.y & ~15) + ((pc ^ (of.y & 15)) << 4));
      half8 v2 = *(const half8*)(xbb + (of.z & ~15) + ((pc ^ (of.z & 15)) << 4));
      half8 v3 = *(const half8*)(xbb + (of.w & ~15) + ((pc ^ (of.w & 15)) << 4));
      half8 a = __builtin_elementwise_max(v0, v1);
      half8 c = __builtin_elementwise_max(v2, v3);
      r8s[i] = __builtin_elementwise_max(a, c);
    }
    int dg0 = (dlc < 9)  ? (g * 36 + dl0)
            : (dlc < 21) ? (576 + g * 48 + (dl0 - 36))
                         : (1344 + g * 48 + (dl0 - 84));
    _Float16* dp = descF + (m00 + pc * 8) * 2112 + dg0;
#pragma unroll
    for (int e = 0; e < 8; ++e) {
      half4 o;
      o[0] = r8s[0][e]; o[1] = r8s[1][e]; o[2] = r8s[2][e]; o[3] = r8s[3][e];
      *(half4*)(dp + (long)e * 2112) = o;   // 8B store, 8B-aligned
    }
  }
}

// ---------------- kGemm1: split-K partial GEMM, LDS-staged via global_load_lds ----------
// grid = 196 Mtiles x 6 K-chunks = 1176 blocks; 256 threads; M=64, N=96, K-chunk=352, BK=32.
__global__ __launch_bounds__(256) void kGemm1(
    const _Float16* __restrict__ descF, const _Float16* __restrict__ w1f,
    _Float16* __restrict__ pacc) {
  __shared__ _Float16 Ab[2][64 * 32];   // [row*32 + c*8]
  __shared__ _Float16 Bb[2][96 * 32];   // [n*32 + c*8]
  const int t = threadIdx.x;
  const int wv = t >> 6, lane = t & 63, quad = lane >> 4, lr = lane & 15;
  const int mt = blockIdx.x / 6, ck = blockIdx.x % 6;
  const long mblk = (long)mt * 64;

  const long agbase = (mblk + (t >> 2)) * 2112 + ck * 352 + (t & 3) * 8;
  const long bg0 = (long)(t >> 2) * 2112 + ck * 352 + (t & 3) * 8;
  const long bg1 = (long)((256 + t) >> 2) * 2112 + ck * 352 + (t & 3) * 8;
  const int wslot = (t >> 6) * 512;     // wave-uniform LDS base (halves)

  floatx4 acc[6];
#pragma unroll
  for (int j = 0; j < 6; ++j) acc[j] = {0.f, 0.f, 0.f, 0.f};

  gld16(descF + agbase, &Ab[0][wslot]);
  gld16(w1f + bg0, &Bb[0][wslot]);
  if (t < 128) gld16(w1f + bg1, &Bb[0][2048 + wslot]);

  int buf = 0;
  for (int kt = 0; kt < 11; ++kt) {
    __syncthreads();
    if (kt < 10) {
      int off = (kt + 1) * 32;
      gld16(descF + agbase + off, &Ab[buf ^ 1][wslot]);
      gld16(w1f + bg0 + off, &Bb[buf ^ 1][wslot]);
      if (t < 128) gld16(w1f + bg1 + off, &Bb[buf ^ 1][2048 + wslot]);
    }
    half8 af = *(const half8*)(&Ab[buf][(wv * 16 + lr) * 32 + quad * 8]);
#pragma unroll
    for (int j = 0; j < 6; ++j) {
      half8 bf = *(const half8*)(&Bb[buf][(j * 16 + lr) * 32 + quad * 8]);
      acc[j] = __builtin_amdgcn_mfma_f32_16x16x32_f16(af, bf, acc[j], 0, 0, 0);
    }
    buf ^= 1;
  }

  _Float16* pp = pacc + (long)(ck * 196 + mt) * 6144;
#pragma unroll
  for (int j = 0; j < 6; ++j)
#pragma unroll
    for (int r = 0; r < 4; ++r)
      pp[(wv * 16 + quad * 4 + r) * 96 + j * 16 + lr] = (_Float16)acc[j][r];
}

// ---------------- kGemm2 v2: reduce(6 pacc)+BN+ReLU -> y tile -> GEMM2 -> softmax ------
// grid = 392 blocks x 256 threads; 32 rows per block; waves = 2(row-half) x 2(col-half).
__global__ __launch_bounds__(256) void kGemm2(
    const _Float16* __restrict__ pacc,
    const float* __restrict__ gamma, const float* __restrict__ beta,
    const float* __restrict__ mean, const float* __restrict__ var,
    const _Float16* __restrict__ w2f, const _Float16* __restrict__ w3f,
    const float* __restrict__ b2, const float* __restrict__ b3,
    _Float16* __restrict__ wtg) {
  __shared__ __align__(16) char smem[24576];
  _Float16* ytF = (_Float16*)smem;        // [0, 6656): 32*104 fp16 (dead after MFMA loop)
  float* wal = (float*)smem;              // [0, 12288): 32*96 f32 (after ytF dead)
  float* wbl = wal + 3072;                // [12288, 24576)
  __shared__ float invv[96], biasv[96];

  const int t = threadIdx.x;
  const int wv = t >> 6, lane = t & 63, quad = lane >> 4, lr = lane & 15;
  const int wr = wv & 1, wc = wv >> 1;
  const long mblk = (long)blockIdx.x * 32;

  if (t < 96) {
    float iv = gamma[t] * rsqrtf(var[t] + 1e-5f);
    invv[t] = iv; biasv[t] = beta[t] - mean[t] * iv;
  }
  __syncthreads();

  // stage: sum 6 split-K slices + BN + ReLU -> ytF [32][104]; 768 quads / 256 threads
#pragma unroll
  for (int i = 0; i < 3; ++i) {
    int q = t + i * 256;                  // 0..767
    int m = q / 24, nq = (q - m * 24) * 4;
    long gbase = (mblk + m) * 96 + nq;
    float s0 = 0.f, s1 = 0.f, s2 = 0.f, s3 = 0.f;
#pragma unroll
    for (int ck = 0; ck < 6; ++ck) {
      half4 v = *(const half4*)(pacc + (long)ck * 1204224 + gbase);
      s0 += (float)v.x; s1 += (float)v.y; s2 += (float)v.z; s3 += (float)v.w;
    }
    half4 o;
    o.x = (_Float16)fmaxf(s0 * invv[nq + 0] + biasv[nq + 0], 0.f);
    o.y = (_Float16)fmaxf(s1 * invv[nq + 1] + biasv[nq + 1], 0.f);
    o.z = (_Float16)fmaxf(s2 * invv[nq + 2] + biasv[nq + 2], 0.f);
    o.w = (_Float16)fmaxf(s3 * invv[nq + 3] + biasv[nq + 3], 0.f);
    *(half4*)(ytF + m * 104 + nq) = o;
  }
  __syncthreads();

  floatx4 aa[3], ab[3];
#pragma unroll
  for (int j = 0; j < 3; ++j) { aa[j] = {0.f,0.f,0.f,0.f}; ab[j] = {0.f,0.f,0.f,0.f}; }
#pragma unroll
  for (int ks = 0; ks < 3; ++ks) {
    half8 af = *(const half8*)(ytF + (wr * 16 + lr) * 104 + ks * 32 + quad * 8);
#pragma unroll
    for (int j = 0; j < 3; ++j) {
      int n = (wc * 3 + j) * 16 + lr;
      int wo = n * 96 + ks * 32 + quad * 8;
      half8 b2v = *(const half8*)(w2f + wo);
      half8 b3v = *(const half8*)(w3f + wo);
      aa[j] = __builtin_amdgcn_mfma_f32_16x16x32_f16(af, b2v, aa[j], 0, 0, 0);
      ab[j] = __builtin_amdgcn_mfma_f32_16x16x32_f16(af, b3v, ab[j], 0, 0, 0);
    }
  }
  __syncthreads();   // ytF dead; smem becomes wal/wbl

#pragma unroll
  for (int j = 0; j < 3; ++j) {
    int n = (wc * 3 + j) * 16 + lr;
    float bb2 = b2[n], bb3 = b3[n];
#pragma unroll
    for (int r = 0; r < 4; ++r) {
      int m = wr * 16 + quad * 4 + r;
      wal[m * 96 + n] = aa[j][r] + bb2;
      wbl[m * 96 + n] = ab[j][r] + bb3;
    }
  }
  __syncthreads();

  // softmax: 32 rows x 64 (g,ns) units = 2048 / 256 threads
#pragma unroll
  for (int it = 0; it < 8; ++it) {
    int u = t + it * 256;
    int m = u >> 6, rest = u & 63;
    int g = rest >> 2, ns = rest & 3;
    int ns1 = ns >> 1, ns2 = ns & 1;
    float la[3], lb[3];
#pragma unroll
    for (int k = 0; k < 3; ++k) {
      la[k] = wal[m * 96 + (g * 3 + k) * 2 + ns1];
      lb[k] = wbl[m * 96 + (g * 3 + k) * 2 + ns2];
    }
    float lg[9], mx = -1e30f;
#pragma unroll
    for (int k1 = 0; k1 < 3; ++k1)
#pragma unroll
      for (int k2 = 0; k2 < 3; ++k2) {
        float v = la[k1] * lb[k2];
        lg[k1 * 3 + k2] = v;
        mx = v > mx ? v : mx;
      }
    float s = 0.f;
#pragma unroll
    for (int k = 0; k < 9; ++k) { lg[k] = __expf(lg[k] - mx); s += lg[k]; }
    float sc = 1.f / (9.f * s);
    _Float16* dst = wtg + (mblk + m) * 576 + g * 36 + ns * 9;
#pragma unroll
    for (int k = 0; k < 9; ++k) dst[k] = (_Float16)(lg[k] * sc);
  }
}

// ---------------- kApply: x + wt -> out; branch-free fill (round-9 v2) ----------
// block = (b, h', wh(2), g(16)): 7168 blocks, 256 threads; 16 channels, 28 w-positions.
__global__ __launch_bounds__(256) void kApply(const float* __restrict__ x,
                                              const _Float16* __restrict__ wt,
                                              float* __restrict__ out) {
  int bid = blockIdx.x;
  int g = bid & 15;
  int wh = (bid >> 4) & 1;
  int h = (bid >> 5) % 56;
  int b = bid / 1792;
  int wbase = wh * 28, cbase = g * 16;

  __shared__ _Float16 xr[9 * 16 * 30];       // [(k2*3+k1)*480 + cl*30 + wc]
  __shared__ __align__(16) float wtb[28 * 36]; // [p*36 + (k1*3+k2)*4 + ns]
  __shared__ float ob[32 * 57];              // [(cl*2+ns1)*57 + p*2+ns2]

  int t = threadIdx.x;

  // fill xr: 144 rows x 30 cols; clamped unconditional loads + selects (no branches)
  {
    int wc = t & 31;
    int r0 = t >> 5;                    // 0..7
    int wr = wbase + wc - 1;
    int wrc = min(max(wr, 0), 55);
    bool cok = (wc < 30) & ((unsigned)wr < 56u);
    const long xb0 = ((long)b * 256 + cbase) * 3136;
    float vals[18];
#pragma unroll
    for (int i = 0; i < 18; ++i) {
      int row = r0 + i * 8;             // 0..143
      int kk = row >> 4, cl = row & 15;
      int k2 = (kk >= 6) ? 2 : (kk >= 3 ? 1 : 0);
      int k1 = kk - 3 * k2;
      int t2 = k2 * 56 + h;
      int q3 = (t2 * 683) >> 11;        // t2/3
      int gr = q3 + k1 - 1;
      int grc = min(max(gr, 0), 55);
      float v = x[xb0 + (long)cl * 3136 + (long)grc * 56 + wrc];
      vals[i] = (cok & ((unsigned)gr < 56u)) ? v : 0.f;
    }
#pragma unroll
    for (int i = 0; i < 18; ++i) {
      int row = r0 + i * 8;
      if (wc < 30) xr[row * 30 + wc] = (_Float16)vals[i];
    }
  }
  // wt -> wtb via half4 loads: unit t<252 = (p 0..27, j 0..8); row segment is 36
  // contiguous halves wt[(m0+p)*576 + g*36 + u], u = ns*9+kk; transpose in regs.
  {
    long m0 = ((long)(b * 56 + h)) * 56 + wbase;
    if (t < 252) {
      int p = t / 9, j = t - p * 9;
      half4 v = *(const half4*)(wt + (m0 + p) * 576 + g * 36 + j * 4);
#pragma unroll
      for (int e = 0; e < 4; ++e) {
        int u = j * 4 + e;              // 0..35
        int ns = (u * 57) >> 9;         // u/9 (exact for u<36)
        int kk = u - ns * 9;
        wtb[p * 36 + kk * 4 + ns] = (float)v[e];
      }
    }
  }
  __syncthreads();

  // compute: thread owns (cl, p); 4 ns accumulators; float4 weight reads
  {
    int j2r[3];
#pragma unroll
    for (int k2 = 0; k2 < 3; ++k2) j2r[k2] = (k2 * 56 + h) % 3;
#pragma unroll
    for (int i = 0; i < 2; ++i) {
      int idx = i * 256 + t;
      int cl = idx & 15;
      int p = idx >> 4;                 // 0..31
      if (p < 28) {
        float a0 = 0.f, a1 = 0.f, a2 = 0.f, a3 = 0.f;
#pragma unroll
        for (int k1 = 0; k1 < 3; ++k1)
#pragma unroll
          for (int k2 = 0; k2 < 3; ++k2) {
            float xv = (float)xr[(k2 * 3 + k1) * 480 + cl * 30 + p + j2r[k2]];
            float4 wv = *(const float4*)&wtb[p * 36 + (k1 * 3 + k2) * 4];
            a0 += xv * wv.x; a1 += xv * wv.y; a2 += xv * wv.z; a3 += xv * wv.w;
          }
        int ob0 = cl * 114 + p * 2;
        ob[ob0] = a0;
        ob[ob0 + 1] = a1;
        ob[ob0 + 57] = a2;
        ob[ob0 + 58] = a3;
      }
    }
  }
  __syncthreads();

  // writeout: 32 rows x 56 cols, coalesced
  {
    int wo = t & 63;
    int r0 = t >> 6;                    // 0..3
    const long obase = (((long)b * 256 + cbase) * 112 + 2 * h) * 112 + wh * 56;
#pragma unroll
    for (int i = 0; i < 8; ++i) {
      int row = r0 + i * 4;             // 0..31
      if (wo < 56) {
        int cli = row >> 1, n1 = row & 1;
        out[obase + cli * 12544 + n1 * 112 + wo] = ob[row * 57 + wo];
      }
    }
  }
}

extern "C" void kernel_launch(void* const* d_in, const int* in_sizes, int n_in,
                              void* d_out, int out_size, void* d_ws, size_t ws_size,
                              hipStream_t stream) {
  const float* x = (const float*)d_in[0];
  const float* w1 = (const float*)d_in[1];
  const float* gamma = (const float*)d_in[2];
  const float* beta = (const float*)d_in[3];
  const float* mean = (const float*)d_in[4];
  const float* var = (const float*)d_in[5];
  const float* w2 = (const float*)d_in[6];
  const float* b2 = (const float*)d_in[7];
  const float* w3 = (const float*)d_in[8];
  const float* b3 = (const float*)d_in[9];
  float* out = (float*)d_out;

  // workspace layout (bytes), total ~82 MB:
  //   w1f fp16:   [0, 405504)
  //   w2f fp16:   [405504, 423936)
  //   w3f fp16:   [423936, 442368)
  //   wtg fp16:   [442368, 14893056)
  //   descF fp16: [14893056, 67878912)
  //   pacc fp16:  [67878912, 82329600)   (6 split-K slices)
  _Float16* w1f = (_Float16*)d_ws;
  _Float16* w2f = w1f + 202752;
  _Float16* w3f = w2f + 9216;
  _Float16* wtg = (_Float16*)((char*)d_ws + 442368);
  _Float16* descF = (_Float16*)((char*)d_ws + 14893056);
  _Float16* pacc = (_Float16*)((char*)d_ws + 67878912);

  hipLaunchKernelGGL(kDescC, dim3(3800), dim3(256), 0, stream,
                     x, w1, w2, w3, descF, w1f, w2f, w3f);
  hipLaunchKernelGGL(kGemm1, dim3(1176), dim3(256), 0, stream, descF, w1f, pacc);
  hipLaunchKernelGGL(kGemm2, dim3(392), dim3(256), 0, stream,
                     pacc, gamma, beta, mean, var, w2f, w3f, b2, b3, wtg);
  hipLaunchKernelGGL(kApply, dim3(7168), dim3(256), 0, stream, x, wtg, out);
}